// Round 14
// baseline (168.682 us; speedup 1.0000x reference)
//
#include <hip/hip_runtime.h>

typedef _Float16 f16;
typedef _Float16 f16x2 __attribute__((ext_vector_type(2)));
typedef _Float16 f16x8 __attribute__((ext_vector_type(8)));
typedef float f32x4 __attribute__((ext_vector_type(4)));
typedef unsigned int u32;
typedef unsigned int u32x4 __attribute__((ext_vector_type(4)));

static __device__ __forceinline__ u32 pk2(float lo, float hi) {
  union { f16 h[2]; u32 u; } v;
  v.h[0] = (f16)lo; v.h[1] = (f16)hi;
  return v.u;
}

// ---- fused prep: blocks 0..2047: W[f,d,e]->fp16 retile;
//      blocks 2048..2079: decayed prefix scan -> st2 PACKED half2 e-pairs.
// W layout: byte = d*32768 + (e>>5)*8192 + f*64 + ((e>>3)&3)*16 + (e&7)*2
// st2 layout: st2[(e>>1)*8192 + b*2048 + t] = pk2(s[t,e], s[t,e+1])
// scan: s[b,0]=0; s[b,t]=(s[b,t-1]+x[b,t-1])/1.2; 64-token chunks with
// 64-token lookback (1.2^-64 ~ 8.5e-6 rel).
__global__ void k_pre(const float* __restrict__ W, char* __restrict__ wt,
                      const float* __restrict__ x, u32* __restrict__ st2) {
  int bid = blockIdx.x;
  if (bid < 2048) {
    int t = bid * 256 + threadIdx.x;
    long i = (long)t * 4;                      // 2M W elements, 4/thread
    int f = (int)(i >> 14);
    int k = (int)(i & 16383);
    float4 w4 = *(const float4*)(W + i);
    int d = k >> 7, e = k & 127;
    long byo = (long)d * 32768 + (e >> 5) * 8192 + f * 64 + ((e >> 3) & 3) * 16 + (e & 7) * 2;
    u32* dst = (u32*)(wt + byo);
    dst[0] = pk2(w4.x, w4.y);
    dst[1] = pk2(w4.z, w4.w);
  } else {
    int tid = (bid - 2048) * 256 + threadIdx.x;   // 8192 threads: e-pairs
    int e2 = tid & 63;
    int bc = tid >> 6;          // 0..127
    int b  = bc >> 5;
    int ch = bc & 31;
    int t0 = ch * 64;
    const float* xb = x + (long)b * 2048 * 128 + 2 * e2;
    u32* sb = st2 + (long)e2 * 8192 + b * 2048;
    const float inv = 1.0f / 1.2f;
    float c0 = 0.f, c1 = 0.f;
    if (ch > 0) {
      const float* xp = xb + (long)(t0 - 64) * 128;
      #pragma unroll
      for (int t = 0; t < 64; ++t) {
        float2 v = *(const float2*)(xp + t * 128);
        c0 = (c0 + v.x) * inv; c1 = (c1 + v.y) * inv;
      }
    }
    const float* xq = xb + (long)t0 * 128;
    u32* sq = sb + t0;
    #pragma unroll
    for (int t = 0; t < 64; ++t) {
      sq[t] = pk2(c0, c1);
      float2 v = *(const float2*)(xq + t * 128);
      c0 = (c0 + v.x) * inv; c1 = (c1 + v.y) * inv;
    }
  }
}

// ---- final reduce: out = sum over 4 K-split partials ----------------------
__global__ void k_red(const float4* __restrict__ part, float4* __restrict__ out) {
  int i = blockIdx.x * 256 + threadIdx.x;          // 262144 float4
  float4 s = part[i];
  #pragma unroll
  for (int q = 1; q < 4; ++q) {
    float4 p = part[i + (long)q * 262144];
    s.x += p.x; s.y += p.y; s.z += p.z; s.w += p.w;
  }
  out[i] = s;
}

// ---------------- main (R7 16x16 skeleton + 3 fixes) + diag variants -------
// grid 256 = 64 tt x K-split 4 -> 1 block/CU. 8 waves = f-half(ng) x
// e-quadrant(ep), disjoint W slices. MODE 0: production. MODE 1: no-epilogue
// (prologue+loop; acc live via store). MODE 2: no-loop (laundered-false
// guard; prologue+epilogue). REP: repeat count (diag visibility in top-5).
template <int MODE, int REP>
__global__ __launch_bounds__(512, 2) void k_mainT(
    const float* __restrict__ x, const u32* __restrict__ st2,
    const char* __restrict__ wt, float* __restrict__ outp) {
  __shared__ __attribute__((aligned(128))) char lds[2 * 128 * 129 * 4]; // 132KB
  u32* x_lds = (u32*)lds;              // [128][36] half2(x,x), aliases red
  float* red = (float*)lds;            // [2][128][129] epilogue buffers

  const int tid  = threadIdx.x;
  const int bid  = blockIdx.x;
  const int kq   = bid & 3;          // K-quarter: d in [kq*32, kq*32+32)
  const int tt   = bid >> 2;         // token tile (0..63)
  const int wv   = tid >> 6;         // 0..7
  const int lane = tid & 63;
  const int ng   = wv & 1;           // f half
  const int ep   = wv >> 1;          // e quadrant
  const int r    = lane & 15;
  const int kg   = lane >> 4;
  const int tokenBase = tt * 128;

  const char* wtq = wt + (long)(kq * 32) * 32768 + ep * 8192 + ng * 4096;
  const int loff = r * 64 + kg * 16;

  int lz0 = 0;
  __asm__ volatile("" : "+v"(lz0));    // laundered 0 (MODE 2 loop guard)

  #pragma unroll 1
  for (int rep = 0; rep < REP; ++rep) {
    __syncthreads();   // prior rep's red reads done before x_lds overwrite

    // stage x tile as duplicated half2 (xv,xv): [128 tok][32 d], d=kq*32+it
    {
      int row = tid >> 2, c0 = (tid & 3) * 8;
      const float* src = x + (long)(tokenBase + row) * 128 + kq * 32 + c0;
      float4 v0 = *(const float4*)src;
      float4 v1 = *(const float4*)(src + 4);
      u32* dst = &x_lds[row * 36 + c0];
      dst[0] = pk2(v0.x, v0.x); dst[1] = pk2(v0.y, v0.y);
      dst[2] = pk2(v0.z, v0.z); dst[3] = pk2(v0.w, v0.w);
      dst[4] = pk2(v1.x, v1.x); dst[5] = pk2(v1.y, v1.y);
      dst[6] = pk2(v1.z, v1.z); dst[7] = pk2(v1.w, v1.w);
    }

    // s: packed half2 pairs straight from st2 (coalesced over r). 32 loads.
    u32 sreg[8][4];
    {
      const u32* stb = st2 + (long)(ep * 16 + kg * 4) * 8192 + tokenBase;
      #pragma unroll
      for (int mr = 0; mr < 8; ++mr)
        #pragma unroll
        for (int jj = 0; jj < 4; ++jj)
          sreg[mr][jj] = stb[(long)jj * 8192 + mr * 16 + r];
    }

    f16x8 ba[4], bb[4];
#define BLOAD(BUF, IT)                                                       \
    {                                                                        \
      int itc = (IT) > 31 ? 31 : (IT);                                       \
      const char* wn = wtq + (long)itc * 32768;                              \
      _Pragma("unroll")                                                      \
      for (int n = 0; n < 4; ++n)                                            \
        BUF[n] = *(const f16x8*)(wn + n * 1024 + loff);                      \
    }
    BLOAD(ba, 0);      // hoisted: B latency overlaps prologue + barrier
    __syncthreads();   // x_lds ready

    f32x4 acc[8][4];
    #pragma unroll
    for (int mr = 0; mr < 8; ++mr)
      #pragma unroll
      for (int n = 0; n < 4; ++n) acc[mr][n] = (f32x4){0.f, 0.f, 0.f, 0.f};

#define STEP(BUF, XB, J)                                                     \
    {                                                                        \
      _Pragma("unroll")                                                      \
      for (int mr = 0; mr < 8; ++mr) {                                       \
        f16x2 xv2;                                                           \
        *(u32*)&xv2 = XB[mr][J];                                             \
        union { u32 u[4]; f16x8 v; } au;                                     \
        _Pragma("unroll")                                                    \
        for (int jj = 0; jj < 4; ++jj) {                                     \
          f16x2 s2;                                                          \
          *(u32*)&s2 = sreg[mr][jj];                                         \
          f16x2 p = xv2 * s2;                                                \
          au.u[jj] = *(u32*)&p;                                              \
        }                                                                    \
        _Pragma("unroll")                                                    \
        for (int n = 0; n < 4; ++n)                                          \
          acc[mr][n] = __builtin_amdgcn_mfma_f32_16x16x32_f16(               \
              au.v, BUF[n], acc[mr][n], 0, 0, 0);                            \
      }                                                                      \
    }

    if (MODE != 2 || lz0 != 0) {       // MODE2: runtime-false, code kept
      #pragma unroll 1
      for (int it4 = 0; it4 < 8; ++it4) {
        u32x4 xb[8];
        #pragma unroll
        for (int mr = 0; mr < 8; ++mr)
          xb[mr] = *(const u32x4*)&x_lds[(mr * 16 + r) * 36 + it4 * 4];
        int it = it4 * 4;
        BLOAD(bb, it + 1); STEP(ba, xb, 0);
        BLOAD(ba, it + 2); STEP(bb, xb, 1);
        BLOAD(bb, it + 3); STEP(ba, xb, 2);
        BLOAD(ba, it + 4); STEP(bb, xb, 3);
      }
    }
#undef STEP
#undef BLOAD

    if constexpr (MODE == 1) {
      // no-epilogue diag: keep acc live with a minimal store
      float ssum = 0.f;
      #pragma unroll
      for (int mr = 0; mr < 8; ++mr)
        #pragma unroll
        for (int n = 0; n < 4; ++n)
          #pragma unroll
          for (int q2 = 0; q2 < 4; ++q2) ssum += acc[mr][n][q2];
      outp[(long)bid * 512 + tid] = ssum;
    } else {
      // epilogue: 2-round parallel reduce (ep0/ep2 write, ep1/ep3 add)
      __syncthreads();   // x_lds dead; red aliasing safe
      float* rb = red + (ep >> 1) * 16512;   // 128*129
      if (!(ep & 1)) {
        #pragma unroll
        for (int mr = 0; mr < 8; ++mr)
          #pragma unroll
          for (int n = 0; n < 4; ++n)
            #pragma unroll
            for (int q2 = 0; q2 < 4; ++q2) {
              int idx = (mr * 16 + kg * 4 + q2) * 129 + ng * 64 + n * 16 + r;
              rb[idx] = acc[mr][n][q2];
            }
      }
      __syncthreads();
      if (ep & 1) {
        #pragma unroll
        for (int mr = 0; mr < 8; ++mr)
          #pragma unroll
          for (int n = 0; n < 4; ++n)
            #pragma unroll
            for (int q2 = 0; q2 < 4; ++q2) {
              int idx = (mr * 16 + kg * 4 + q2) * 129 + ng * 64 + n * 16 + r;
              rb[idx] += acc[mr][n][q2];
            }
      }
      __syncthreads();
      float* op = outp + (long)kq * 1048576 + (long)tokenBase * 128;
      #pragma unroll
      for (int j = 0; j < 32; ++j) {
        int row = (tid >> 7) + j * 4;
        int col = tid & 127;
        op[row * 128 + col] = red[row * 129 + col] + red[16512 + row * 129 + col];
      }
    }
  }
}

extern "C" void kernel_launch(void* const* d_in, const int* in_sizes, int n_in,
                              void* d_out, int out_size, void* d_ws, size_t ws_size,
                              hipStream_t stream) {
  const float* x = (const float*)d_in[0];        // [4,2048,128] f32
  const float* W = (const float*)d_in[1];        // [128,128,128] f32
  float* out  = (float*)d_out;                   // [4,2048,128] f32
  u32*   st2  = (u32*)d_ws;                      // 2 MB: s packed half2 pairs
  char*  wt   = (char*)d_ws + (4 << 20);         // 4 MB: W fp16 retiled
  float* part = (float*)((char*)d_ws + (8 << 20));  // 16 MB: K-split partials
  float* scr  = (float*)((char*)d_ws + (24 << 20)); // 16 MB: diag scratch

  k_pre<<<dim3(2080), dim3(256), 0, stream>>>(W, wt, x, st2);
  // diagnostics (write scratch only; also warm L2 for production):
  k_mainT<1, 2><<<dim3(256), dim3(512), 0, stream>>>(x, st2, wt, scr); // prologue+loop x2
  k_mainT<2, 8><<<dim3(256), dim3(512), 0, stream>>>(x, st2, wt, scr); // prologue+epilogue x8
  // production:
  k_mainT<0, 1><<<dim3(256), dim3(512), 0, stream>>>(x, st2, wt, part);
  k_red<<<dim3(1024), dim3(256), 0, stream>>>((const float4*)part, (float4*)out);
}

// Round 15
// 54.289 us; speedup vs baseline: 3.1071x; 3.1071x over previous
//
#include <hip/hip_runtime.h>

typedef _Float16 f16;
typedef _Float16 f16x2 __attribute__((ext_vector_type(2)));
typedef _Float16 f16x8 __attribute__((ext_vector_type(8)));
typedef float f32x4 __attribute__((ext_vector_type(4)));
typedef unsigned int u32;
typedef unsigned int u32x4 __attribute__((ext_vector_type(4)));

static __device__ __forceinline__ u32 pk2(float lo, float hi) {
  union { f16 h[2]; u32 u; } v;
  v.h[0] = (f16)lo; v.h[1] = (f16)hi;
  return v.u;
}

// ---- fused prep: blocks 0..2047: W[f,d,e]->fp16 retile, XCD-PINNED;
//      blocks 2048..2079: decayed prefix scan -> st2 PACKED half2 e-pairs.
// W layout: byte = d*32768 + (e>>5)*8192 + f*64 + ((e>>3)&3)*16 + (e&7)*2
// Pinning: retile block bid does canonical block w's work, w_low4 =
// ((b4&3)<<2)|((b4>>2)&3) (bijective nibble swap). Block w covers d-octet
// (w&15)*8..+8, i.e. d-quarter (w&15)>>2. With this swap, the quarter
// written by XCD x (= bid%8) is x&3 -- exactly the quarter k_main blocks
// on XCD x read (kq = bid&3, and (bid+8j)&3 is XCD-invariant). W lines are
// born dirty in the right L2.
__global__ void k_pre(const float* __restrict__ W, char* __restrict__ wt,
                      const float* __restrict__ x, u32* __restrict__ st2) {
  int bid = blockIdx.x;
  if (bid < 2048) {
    int b4 = bid & 15;
    int w  = (bid & ~15) | ((b4 & 3) << 2) | ((b4 >> 2) & 3);
    int t = w * 256 + threadIdx.x;
    long i = (long)t * 4;                      // 2M W elements, 4/thread
    int f = (int)(i >> 14);
    int k = (int)(i & 16383);
    float4 w4 = *(const float4*)(W + i);
    int d = k >> 7, e = k & 127;
    long byo = (long)d * 32768 + (e >> 5) * 8192 + f * 64 + ((e >> 3) & 3) * 16 + (e & 7) * 2;
    u32* dst = (u32*)(wt + byo);
    dst[0] = pk2(w4.x, w4.y);
    dst[1] = pk2(w4.z, w4.w);
  } else {
    int tid = (bid - 2048) * 256 + threadIdx.x;   // 8192 threads: e-pairs
    int e2 = tid & 63;
    int bc = tid >> 6;          // 0..127
    int b  = bc >> 5;
    int ch = bc & 31;
    int t0 = ch * 64;
    const float* xb = x + (long)b * 2048 * 128 + 2 * e2;
    u32* sb = st2 + (long)e2 * 8192 + b * 2048;
    const float inv = 1.0f / 1.2f;
    float c0 = 0.f, c1 = 0.f;
    if (ch > 0) {
      const float* xp = xb + (long)(t0 - 64) * 128;
      #pragma unroll
      for (int t = 0; t < 64; ++t) {
        float2 v = *(const float2*)(xp + t * 128);
        c0 = (c0 + v.x) * inv; c1 = (c1 + v.y) * inv;
      }
    }
    const float* xq = xb + (long)t0 * 128;
    u32* sq = sb + t0;
    #pragma unroll
    for (int t = 0; t < 64; ++t) {
      sq[t] = pk2(c0, c1);
      float2 v = *(const float2*)(xq + t * 128);
      c0 = (c0 + v.x) * inv; c1 = (c1 + v.y) * inv;
    }
  }
}

// ---- final reduce: out = sum over 4 K-split partials ----------------------
__global__ void k_red(const float4* __restrict__ part, float4* __restrict__ out) {
  int i = blockIdx.x * 256 + threadIdx.x;          // 262144 float4
  float4 s = part[i];
  #pragma unroll
  for (int q = 1; q < 4; ++q) {
    float4 p = part[i + (long)q * 262144];
    s.x += p.x; s.y += p.y; s.z += p.z; s.w += p.w;
  }
  out[i] = s;
}

// ---------------- main: part[kq][token,f] = sum_{d in kq} (x*s) W ----------
// grid 256 = 64 tt x K-split 4 -> 1 block/CU; XCD x reads only W quarter
// x&3 (local-dirty via pinned k_pre). 8 waves = f-half(ng) x e-quadrant(ep),
// disjoint W slices. 16x16x32 f16 MFMA; register ping-pong B; st2 packed;
// hoisted tile-0 B load; 2-round parallel reduce; float4 part stores.
__global__ __launch_bounds__(512, 2) void k_main(
    const float* __restrict__ x, const u32* __restrict__ st2,
    const char* __restrict__ wt, float* __restrict__ part) {
  __shared__ __attribute__((aligned(128))) char lds[2 * 128 * 129 * 4]; // 132KB
  u32* x_lds = (u32*)lds;              // [128][36] half2(x,x), aliases red
  float* red = (float*)lds;            // [2][128][129] epilogue buffers

  const int tid  = threadIdx.x;
  const int bid  = blockIdx.x;
  const int kq   = bid & 3;          // K-quarter: d in [kq*32, kq*32+32)
  const int tt   = bid >> 2;         // token tile (0..63)
  const int wv   = tid >> 6;         // 0..7
  const int lane = tid & 63;
  const int ng   = wv & 1;           // f half
  const int ep   = wv >> 1;          // e quadrant
  const int r    = lane & 15;
  const int kg   = lane >> 4;
  const int tokenBase = tt * 128;

  const char* wtq = wt + (long)(kq * 32) * 32768 + ep * 8192 + ng * 4096;
  const int loff = r * 64 + kg * 16;

  // stage x tile as duplicated half2 (xv,xv): [128 tok][32 d], d = kq*32+it
  {
    int row = tid >> 2, c0 = (tid & 3) * 8;
    const float* src = x + (long)(tokenBase + row) * 128 + kq * 32 + c0;
    float4 v0 = *(const float4*)src;
    float4 v1 = *(const float4*)(src + 4);
    u32* dst = &x_lds[row * 36 + c0];
    dst[0] = pk2(v0.x, v0.x); dst[1] = pk2(v0.y, v0.y);
    dst[2] = pk2(v0.z, v0.z); dst[3] = pk2(v0.w, v0.w);
    dst[4] = pk2(v1.x, v1.x); dst[5] = pk2(v1.y, v1.y);
    dst[6] = pk2(v1.z, v1.z); dst[7] = pk2(v1.w, v1.w);
  }

  // s: packed half2 pairs straight from st2 (coalesced over r). 32 loads.
  u32 sreg[8][4];
  {
    const u32* stb = st2 + (long)(ep * 16 + kg * 4) * 8192 + tokenBase;
    #pragma unroll
    for (int mr = 0; mr < 8; ++mr)
      #pragma unroll
      for (int jj = 0; jj < 4; ++jj)
        sreg[mr][jj] = stb[(long)jj * 8192 + mr * 16 + r];
  }

  f16x8 ba[4], bb[4];
#define BLOAD(BUF, IT)                                                       \
  {                                                                          \
    int itc = (IT) > 31 ? 31 : (IT);                                         \
    const char* wn = wtq + (long)itc * 32768;                                \
    _Pragma("unroll")                                                        \
    for (int n = 0; n < 4; ++n)                                              \
      BUF[n] = *(const f16x8*)(wn + n * 1024 + loff);                        \
  }
  BLOAD(ba, 0);      // hoisted: B latency overlaps prologue + barrier
  __syncthreads();   // x_lds ready

  f32x4 acc[8][4];
  #pragma unroll
  for (int mr = 0; mr < 8; ++mr)
    #pragma unroll
    for (int n = 0; n < 4; ++n) acc[mr][n] = (f32x4){0.f, 0.f, 0.f, 0.f};

#define STEP(BUF, XB, J)                                                     \
  {                                                                          \
    _Pragma("unroll")                                                        \
    for (int mr = 0; mr < 8; ++mr) {                                         \
      f16x2 xv2;                                                             \
      *(u32*)&xv2 = XB[mr][J];                                               \
      union { u32 u[4]; f16x8 v; } au;                                       \
      _Pragma("unroll")                                                      \
      for (int jj = 0; jj < 4; ++jj) {                                       \
        f16x2 s2;                                                            \
        *(u32*)&s2 = sreg[mr][jj];                                           \
        f16x2 p = xv2 * s2;                                                  \
        au.u[jj] = *(u32*)&p;                                                \
      }                                                                      \
      _Pragma("unroll")                                                      \
      for (int n = 0; n < 4; ++n)                                            \
        acc[mr][n] = __builtin_amdgcn_mfma_f32_16x16x32_f16(                 \
            au.v, BUF[n], acc[mr][n], 0, 0, 0);                              \
    }                                                                        \
  }

  #pragma unroll 1
  for (int it4 = 0; it4 < 8; ++it4) {
    u32x4 xb[8];
    #pragma unroll
    for (int mr = 0; mr < 8; ++mr)
      xb[mr] = *(const u32x4*)&x_lds[(mr * 16 + r) * 36 + it4 * 4];
    int it = it4 * 4;
    BLOAD(bb, it + 1); STEP(ba, xb, 0);
    BLOAD(ba, it + 2); STEP(bb, xb, 1);
    BLOAD(bb, it + 3); STEP(ba, xb, 2);
    BLOAD(ba, it + 4); STEP(bb, xb, 3);
  }
#undef STEP
#undef BLOAD

  // epilogue: 2-round parallel reduce (ep0/ep2 + ep1/ep3), float4 stores
  __syncthreads();   // x_lds dead; red aliasing safe
  float* rb = red + (ep >> 1) * 16512;   // 128*129
  if (!(ep & 1)) {
    #pragma unroll
    for (int mr = 0; mr < 8; ++mr)
      #pragma unroll
      for (int n = 0; n < 4; ++n)
        #pragma unroll
        for (int q2 = 0; q2 < 4; ++q2) {
          int idx = (mr * 16 + kg * 4 + q2) * 129 + ng * 64 + n * 16 + r;
          rb[idx] = acc[mr][n][q2];
        }
  }
  __syncthreads();
  if (ep & 1) {
    #pragma unroll
    for (int mr = 0; mr < 8; ++mr)
      #pragma unroll
      for (int n = 0; n < 4; ++n)
        #pragma unroll
        for (int q2 = 0; q2 < 4; ++q2) {
          int idx = (mr * 16 + kg * 4 + q2) * 129 + ng * 64 + n * 16 + r;
          rb[idx] += acc[mr][n][q2];
        }
  }
  __syncthreads();
  float* op = part + (long)kq * 1048576 + (long)tokenBase * 128;
  #pragma unroll
  for (int j = 0; j < 8; ++j) {
    int row = (tid >> 5) + j * 16;
    int c4  = (tid & 31) * 4;
    int idx = row * 129 + c4;
    float4 v;
    v.x = red[idx]     + red[16512 + idx];
    v.y = red[idx + 1] + red[16512 + idx + 1];
    v.z = red[idx + 2] + red[16512 + idx + 2];
    v.w = red[idx + 3] + red[16512 + idx + 3];
    *(float4*)&op[row * 128 + c4] = v;
  }
}

extern "C" void kernel_launch(void* const* d_in, const int* in_sizes, int n_in,
                              void* d_out, int out_size, void* d_ws, size_t ws_size,
                              hipStream_t stream) {
  const float* x = (const float*)d_in[0];        // [4,2048,128] f32
  const float* W = (const float*)d_in[1];        // [128,128,128] f32
  float* out  = (float*)d_out;                   // [4,2048,128] f32
  u32*   st2  = (u32*)d_ws;                      // 2 MB: s packed half2 pairs
  char*  wt   = (char*)d_ws + (4 << 20);         // 4 MB: W fp16 retiled
  float* part = (float*)((char*)d_ws + (8 << 20)); // 16 MB: K-split partials

  k_pre<<<dim3(2080), dim3(256), 0, stream>>>(W, wt, x, st2);
  k_main<<<dim3(256), dim3(512), 0, stream>>>(x, st2, wt, part);
  k_red<<<dim3(1024), dim3(256), 0, stream>>>((const float4*)part, (float4*)out);
}